// Round 1
// baseline (369.122 us; speedup 1.0000x reference)
//
#include <hip/hip_runtime.h>
#include <stdint.h>

typedef __bf16 bf16x8 __attribute__((ext_vector_type(8)));
typedef float f32x4 __attribute__((ext_vector_type(4)));
typedef unsigned short u16x8 __attribute__((ext_vector_type(8)));

typedef const __attribute__((address_space(1))) void* gas_ptr;
typedef __attribute__((address_space(3))) void* las_ptr;

__device__ __forceinline__ void gload16(const void* g, void* l) {
  __builtin_amdgcn_global_load_lds((gas_ptr)g, (las_ptr)l, 16, 0, 0);
}

__device__ __forceinline__ unsigned short f2bf(float f) {
  uint32_t u = __float_as_uint(f);
  u += 0x7FFFu + ((u >> 16) & 1u);
  return (unsigned short)(u >> 16);
}

// ---------------- f32 -> bf16 conversion ----------------
__device__ __forceinline__ void conv8(const float* __restrict__ src,
                                      unsigned short* __restrict__ dst, int i) {
  const float4* s4 = (const float4*)src;
  float4 a = s4[2 * i], b = s4[2 * i + 1];
  u16x8 r;
  r[0] = f2bf(a.x); r[1] = f2bf(a.y); r[2] = f2bf(a.z); r[3] = f2bf(a.w);
  r[4] = f2bf(b.x); r[5] = f2bf(b.y); r[6] = f2bf(b.z); r[7] = f2bf(b.w);
  *(u16x8*)&dst[(size_t)i * 8] = r;
}

__global__ __launch_bounds__(256) void cvt_f32_bf16(const float* __restrict__ src,
                                                    unsigned short* __restrict__ dst,
                                                    int n8) {
  int i = blockIdx.x * 256 + threadIdx.x;
  if (i < n8) conv8(src, dst, i);
}

// gather selected expert's weight matrix, convert to bf16
__global__ __launch_bounds__(256) void cvt_w_bf16(const float* __restrict__ Wbase,
                                                  const int* __restrict__ eptr,
                                                  unsigned short* __restrict__ dst) {
  const float* src = Wbase + (size_t)(*eptr) * (1024 * 1024);
  int i = blockIdx.x * 256 + threadIdx.x;  // 0..131071
  conv8(src, dst, i);
}

// ---------------- RoPE cos/sin table: [512][128] each ----------------
__global__ __launch_bounds__(256) void rope_table(float* __restrict__ cosb,
                                                  float* __restrict__ sinb) {
  int i = blockIdx.x * 256 + threadIdx.x;  // 0..65535
  int t = i >> 7, d = i & 127;
  int f = d & 63;
  float invf = expf(-0.14391156831212787f * (float)f);  // 10000^(-f/64)
  float ang = (float)t * invf;
  float s, c;
  sincosf(ang, &s, &c);
  cosb[i] = c;
  sinb[i] = s;
}

// ---------------- GEMM: C[M,1024] = A[M,1024] * W[1024,1024]^T (+epilogue) ----
// m97 structure: 128x128 tile, BK=32, 4 waves (2x2), global_load_lds w=16.
// EPI 0: +bias, RoPE, store bf16 (b,h,t,d).   LSEQ in {512,256}
// EPI 1: +bias, store bf16 transposed vT (b,h,d, voff+n)
// EPI 2: +bias +resid, store f32
// EPI 3: +bias, relu, store f32
template <int EPI, int LSEQ>
__global__ __launch_bounds__(256)
void gemm_bt(const unsigned short* __restrict__ A, const unsigned short* __restrict__ Wb,
             const float* __restrict__ bias_base, const int* __restrict__ eptr,
             const float* __restrict__ ctab, const float* __restrict__ stab,
             unsigned short* __restrict__ out_bf, int voff,
             const float* __restrict__ resid, float* __restrict__ out_f32) {
  __shared__ unsigned short As[128 * 32];
  __shared__ unsigned short Bs[128 * 32];
  const int tid = threadIdx.x, lane = tid & 63, wv = tid >> 6;
  const int wr = wv >> 1, wc = wv & 1;
  const int bn = blockIdx.x, bm = blockIdx.y;
  const int e = *eptr;
  const float* bias = bias_base + e * 1024;
  const int srow = tid >> 2, scol = (tid & 3) << 3;
  const unsigned short* Ag = A + (size_t)(bm * 128 + srow) * 1024 + scol;
  const unsigned short* Bg = Wb + (size_t)(bn * 128 + srow) * 1024 + scol;
  unsigned short* Asd = As + tid * 8;
  unsigned short* Bsd = Bs + tid * 8;

  f32x4 acc[4][4];
#pragma unroll
  for (int m = 0; m < 4; ++m)
#pragma unroll
    for (int n = 0; n < 4; ++n) acc[m][n] = f32x4{0.f, 0.f, 0.f, 0.f};

  const int fr = lane & 15, ko = (lane >> 4) << 3;
  for (int kt = 0; kt < 1024; kt += 32) {
    gload16(Ag + kt, Asd);
    gload16(Ag + kt + 65536, Asd + 2048);
    gload16(Bg + kt, Bsd);
    gload16(Bg + kt + 65536, Bsd + 2048);
    __syncthreads();
    bf16x8 af[4], bw[4];
#pragma unroll
    for (int m = 0; m < 4; ++m)
      af[m] = *(const bf16x8*)&As[(wr * 64 + m * 16 + fr) * 32 + ko];
#pragma unroll
    for (int n = 0; n < 4; ++n)
      bw[n] = *(const bf16x8*)&Bs[(wc * 64 + n * 16 + fr) * 32 + ko];
#pragma unroll
    for (int m = 0; m < 4; ++m)
#pragma unroll
      for (int n = 0; n < 4; ++n)
        acc[m][n] = __builtin_amdgcn_mfma_f32_16x16x32_bf16(af[m], bw[n], acc[m][n], 0, 0, 0);
    __syncthreads();
  }

  const int g = lane >> 4;
#pragma unroll
  for (int m = 0; m < 4; ++m) {
#pragma unroll
    for (int n = 0; n < 4; ++n) {
      const int gcol = bn * 128 + wc * 64 + n * 16 + fr;
      const float bv = bias[gcol];
#pragma unroll
      for (int j = 0; j < 4; ++j) {
        const int grow = bm * 128 + wr * 64 + m * 16 + g * 4 + j;
        float v = acc[m][n][j] + bv;
        if constexpr (EPI == 0) {
          constexpr int SH = (LSEQ == 512) ? 9 : 8;
          const int t = grow & (LSEQ - 1);
          const int bb = grow >> SH;
          const int hh = gcol >> 7, dd = gcol & 127;
          float pv = __shfl_xor(v, 1);  // partner column (d^1), incl. its bias
          float cs = ctab[t * 128 + dd], sn = stab[t * 128 + dd];
          float rh = (dd & 1) ? pv : -pv;  // rotate_half interleaved
          float o = v * cs + rh * sn;
          out_bf[(((size_t)(bb * 8 + hh) * LSEQ + t) << 7) + dd] = f2bf(o);
        } else if constexpr (EPI == 1) {
          const int nn = grow & 255, bb = grow >> 8;
          const int hh = gcol >> 7, dd = gcol & 127;
          out_bf[(((size_t)(bb * 8 + hh) << 7) + (size_t)dd) * 512 + voff + nn] = f2bf(v);
        } else if constexpr (EPI == 2) {
          const size_t idx = ((size_t)grow << 10) + gcol;
          out_f32[idx] = v + resid[idx];
        } else {
          const size_t idx = ((size_t)grow << 10) + gcol;
          out_f32[idx] = fmaxf(v, 0.f);
        }
      }
    }
  }
}

// ---------------- fused dual-stream flash attention ----------------
// grid: 512 blocks = (b:16, h:8, q-chunk:4 of 128 rows); 256 thr = 4 waves x 32 rows
// KV tiles of 64: tiles 0-3 -> (QA,KA,VA), tiles 4-7 -> (QT,KT,VT*ratio)
__global__ __launch_bounds__(256)
void attn_kernel(const unsigned short* __restrict__ QA, const unsigned short* __restrict__ QT,
                 const unsigned short* __restrict__ KA, const unsigned short* __restrict__ KT,
                 const unsigned short* __restrict__ VT,  // (b,h,d=128,n=512)
                 unsigned short* __restrict__ AO,        // (b,t,1024)
                 const float* __restrict__ gating, const int* __restrict__ eptr) {
  __shared__ unsigned short Qs[128 * 128];  // 32 KB, XOR-swizzled
  __shared__ unsigned short Ks[64 * 128];   // 16 KB
  __shared__ unsigned short Vs[128 * 64];   // 16 KB  ([d][n])
  __shared__ unsigned short Ps[128 * 64];   // 16 KB
  const int tid = threadIdx.x, lane = tid & 63, wv = tid >> 6;
  const int fr = lane & 15, g = lane >> 4;
  const int bid = blockIdx.x;
  const int b = bid >> 5, h = (bid >> 2) & 7, q0 = (bid & 3) << 7;
  const float ratio = 1.f / (1.f + __expf(-gating[*eptr]));
  const float SC = 0.08838834764831845f;  // 1/sqrt(128)
  const size_t bh = (size_t)(b * 8 + h);

  float m_run[2][4], l_run[2][4];
  f32x4 oacc[2][8];
#pragma unroll
  for (int mb = 0; mb < 2; ++mb) {
#pragma unroll
    for (int j = 0; j < 4; ++j) { m_run[mb][j] = -1e30f; l_run[mb][j] = 0.f; }
#pragma unroll
    for (int db = 0; db < 8; ++db) oacc[mb][db] = f32x4{0.f, 0.f, 0.f, 0.f};
  }
  bf16x8 qf[2][4];

  for (int it = 0; it < 8; ++it) {
    __syncthreads();
    if (it == 0 || it == 4) {  // (re)stage Q tile 128x128
      const unsigned short* src = ((it == 0) ? QA : QT) + ((bh * 512 + q0) << 7);
#pragma unroll
      for (int j = 0; j < 8; ++j) {
        int off = (tid + j * 256) * 8;
        int r = off >> 7, cc = off & 127;
        u16x8 v = *(const u16x8*)&src[r * 128 + cc];
        int byt = (r * 256 + cc * 2) ^ ((r & 7) << 4);
        *(u16x8*)((char*)Qs + byt) = v;
      }
    }
    {  // K tile 64x128
      const unsigned short* kbuf = (it < 4) ? KA : KT;
      int n0 = (it & 3) << 6;
      const unsigned short* src = kbuf + ((bh * 256 + n0) << 7);
#pragma unroll
      for (int j = 0; j < 4; ++j) {
        int off = (tid + j * 256) * 8;
        int r = off >> 7, cc = off & 127;
        u16x8 v = *(const u16x8*)&src[r * 128 + cc];
        int byt = (r * 256 + cc * 2) ^ ((r & 7) << 4);
        *(u16x8*)((char*)Ks + byt) = v;
      }
      // V tile: all 128 d x 64 n from transposed buffer
      const unsigned short* vsrc = VT + (bh << 16) + (it << 6);
#pragma unroll
      for (int j = 0; j < 4; ++j) {
        int off = (tid + j * 256) * 8;
        int d = off >> 6, nn = off & 63;
        u16x8 v = *(const u16x8*)&vsrc[(size_t)d * 512 + nn];
        int byt = (d * 128 + nn * 2) ^ ((d & 7) << 4);
        *(u16x8*)((char*)Vs + byt) = v;
      }
    }
    __syncthreads();
    if (it == 0 || it == 4) {
#pragma unroll
      for (int mb = 0; mb < 2; ++mb)
#pragma unroll
        for (int kb = 0; kb < 4; ++kb) {
          int r = wv * 32 + mb * 16 + fr;
          int byt = (r * 256 + kb * 64 + g * 16) ^ ((r & 7) << 4);
          qf[mb][kb] = *(const bf16x8*)((const char*)Qs + byt);
        }
    }
    const float sc = (it < 4) ? SC : SC * ratio;
    // S = Q K^T  (wave's 32 rows x 64 cols)
    f32x4 s[2][4];
#pragma unroll
    for (int mb = 0; mb < 2; ++mb)
#pragma unroll
      for (int nb = 0; nb < 4; ++nb) s[mb][nb] = f32x4{0.f, 0.f, 0.f, 0.f};
#pragma unroll
    for (int nb = 0; nb < 4; ++nb) {
#pragma unroll
      for (int kb = 0; kb < 4; ++kb) {
        int r = nb * 16 + fr;
        int byt = (r * 256 + kb * 64 + g * 16) ^ ((r & 7) << 4);
        bf16x8 kf = *(const bf16x8*)((const char*)Ks + byt);
        s[0][nb] = __builtin_amdgcn_mfma_f32_16x16x32_bf16(qf[0][kb], kf, s[0][nb], 0, 0, 0);
        s[1][nb] = __builtin_amdgcn_mfma_f32_16x16x32_bf16(qf[1][kb], kf, s[1][nb], 0, 0, 0);
      }
    }
    // scale + online softmax
    float mt[2][4];
#pragma unroll
    for (int mb = 0; mb < 2; ++mb)
#pragma unroll
      for (int j = 0; j < 4; ++j) {
        float mx = -1e30f;
#pragma unroll
        for (int nb = 0; nb < 4; ++nb) {
          s[mb][nb][j] *= sc;
          mx = fmaxf(mx, s[mb][nb][j]);
        }
        mt[mb][j] = mx;
      }
#pragma unroll
    for (int mb = 0; mb < 2; ++mb)
#pragma unroll
      for (int j = 0; j < 4; ++j) {
#pragma unroll
        for (int d = 1; d < 16; d <<= 1) mt[mb][j] = fmaxf(mt[mb][j], __shfl_xor(mt[mb][j], d));
        float mn = fmaxf(m_run[mb][j], mt[mb][j]);
        float alpha = __expf(m_run[mb][j] - mn);
        m_run[mb][j] = mn;
        l_run[mb][j] *= alpha;
#pragma unroll
        for (int db = 0; db < 8; ++db) oacc[mb][db][j] *= alpha;
      }
    // P = exp(S - m); write bf16 to swizzled LDS (packed col pairs)
#pragma unroll
    for (int mb = 0; mb < 2; ++mb)
#pragma unroll
      for (int nb = 0; nb < 4; ++nb) {
        float p[4], po[4];
#pragma unroll
        for (int j = 0; j < 4; ++j) {
          p[j] = __expf(s[mb][nb][j] - m_run[mb][j]);
          l_run[mb][j] += p[j];
        }
#pragma unroll
        for (int j = 0; j < 4; ++j) po[j] = __shfl_xor(p[j], 1);
        if ((lane & 1) == 0) {
#pragma unroll
          for (int j = 0; j < 4; ++j) {
            uint32_t pk = (uint32_t)f2bf(p[j]) | ((uint32_t)f2bf(po[j]) << 16);
            int r = wv * 32 + mb * 16 + g * 4 + j;
            int byt = (r * 128 + (nb * 16 + fr) * 2) ^ ((r & 7) << 4);
            *(uint32_t*)((char*)Ps + byt) = pk;
          }
        }
      }
    // O += P * V  (same-wave LDS write->read, compiler orders via lgkmcnt)
#pragma unroll
    for (int kb2 = 0; kb2 < 2; ++kb2) {
      bf16x8 pf[2];
#pragma unroll
      for (int mb = 0; mb < 2; ++mb) {
        int r = wv * 32 + mb * 16 + fr;
        int byt = (r * 128 + kb2 * 64 + g * 16) ^ ((r & 7) << 4);
        pf[mb] = *(const bf16x8*)((const char*)Ps + byt);
      }
#pragma unroll
      for (int db = 0; db < 8; ++db) {
        int rv = db * 16 + fr;
        int byt = (rv * 128 + kb2 * 64 + g * 16) ^ ((rv & 7) << 4);
        bf16x8 vf = *(const bf16x8*)((const char*)Vs + byt);
        oacc[0][db] = __builtin_amdgcn_mfma_f32_16x16x32_bf16(pf[0], vf, oacc[0][db], 0, 0, 0);
        oacc[1][db] = __builtin_amdgcn_mfma_f32_16x16x32_bf16(pf[1], vf, oacc[1][db], 0, 0, 0);
      }
    }
  }

  // finalize: reduce l over 16-lane group, normalize, store
#pragma unroll
  for (int mb = 0; mb < 2; ++mb)
#pragma unroll
    for (int j = 0; j < 4; ++j) {
      float lt = l_run[mb][j];
#pragma unroll
      for (int d = 1; d < 16; d <<= 1) lt += __shfl_xor(lt, d);
      float inv = 1.f / lt;
#pragma unroll
      for (int db = 0; db < 8; ++db) {
        float o = oacc[mb][db][j] * inv;
        int row = q0 + wv * 32 + mb * 16 + g * 4 + j;
        int col = h * 128 + db * 16 + fr;
        AO[(((size_t)b * 512 + row) << 10) + col] = f2bf(o);
      }
    }
}

// ---------------- LayerNorm (rows of 1024) ----------------
__global__ __launch_bounds__(256)
void ln_kernel(const float* __restrict__ X2, const float* __restrict__ gbase,
               const float* __restrict__ bbase, const int* __restrict__ eptr,
               unsigned short* __restrict__ XN) {
  const int row = blockIdx.x, tid = threadIdx.x;
  const float* x = X2 + ((size_t)row << 10);
  float4 v = ((const float4*)x)[tid];
  float s = v.x + v.y + v.z + v.w;
  float ss = v.x * v.x + v.y * v.y + v.z * v.z + v.w * v.w;
#pragma unroll
  for (int d = 1; d < 64; d <<= 1) {
    s += __shfl_xor(s, d);
    ss += __shfl_xor(ss, d);
  }
  __shared__ float red[8];
  const int wv = tid >> 6, lane = tid & 63;
  if (lane == 0) { red[wv] = s; red[4 + wv] = ss; }
  __syncthreads();
  s = red[0] + red[1] + red[2] + red[3];
  ss = red[4] + red[5] + red[6] + red[7];
  const float mu = s * 0.0009765625f;
  const float var = ss * 0.0009765625f - mu * mu;
  const float inv = rsqrtf(var + 1e-5f);
  const int e = *eptr;
  const float* gg = gbase + e * 1024 + tid * 4;
  const float* bb = bbase + e * 1024 + tid * 4;
  ushort4 o;
  o.x = f2bf((v.x - mu) * inv * gg[0] + bb[0]);
  o.y = f2bf((v.y - mu) * inv * gg[1] + bb[1]);
  o.z = f2bf((v.z - mu) * inv * gg[2] + bb[2]);
  o.w = f2bf((v.w - mu) * inv * gg[3] + bb[3]);
  *(ushort4*)&XN[((size_t)row << 10) + tid * 4] = o;
}

// ---------------- host launcher ----------------
extern "C" void kernel_launch(void* const* d_in, const int* in_sizes, int n_in,
                              void* d_out, int out_size, void* d_ws, size_t ws_size,
                              hipStream_t stream) {
  (void)in_sizes; (void)n_in; (void)out_size; (void)ws_size;
  const float* x      = (const float*)d_in[0];
  const float* h_a    = (const float*)d_in[1];
  const float* h_t    = (const float*)d_in[2];
  const float* W_qa   = (const float*)d_in[3];
  const float* b_qa   = (const float*)d_in[4];
  const float* W_ka   = (const float*)d_in[5];
  const float* b_ka   = (const float*)d_in[6];
  const float* W_va   = (const float*)d_in[7];
  const float* b_va   = (const float*)d_in[8];
  const float* W_qt   = (const float*)d_in[9];
  const float* b_qt   = (const float*)d_in[10];
  const float* W_kt   = (const float*)d_in[11];
  const float* b_kt   = (const float*)d_in[12];
  const float* W_vt   = (const float*)d_in[13];
  const float* b_vt   = (const float*)d_in[14];
  const float* W_o    = (const float*)d_in[15];
  const float* b_o    = (const float*)d_in[16];
  const float* W_ffn  = (const float*)d_in[17];
  const float* b_ffn  = (const float*)d_in[18];
  const float* gamma  = (const float*)d_in[19];
  const float* beta   = (const float*)d_in[20];
  const float* gating = (const float*)d_in[21];
  const int*   eptr   = (const int*)d_in[22];

  char* ws = (char*)d_ws;
  unsigned short* XB  = (unsigned short*)(ws + 0);          // 16 MB (x bf16)
  unsigned short* HAB = (unsigned short*)(ws + 16777216);   // 8 MB
  unsigned short* HTB = (unsigned short*)(ws + 25165824);   // 8 MB
  float*          X2  = (float*)(ws + 0);                   // 32 MB, overlays XB/HAB/HTB (dead by then)
  unsigned short* WW  = (unsigned short*)(ws + 33554432);   // 8 x 2 MB bf16 weights
  unsigned short* QAb = (unsigned short*)(ws + 50331648);   // 16 MB
  unsigned short* XN  = QAb;                                // overlays QA (dead after attn)
  unsigned short* QTb = (unsigned short*)(ws + 67108864);   // 16 MB
  unsigned short* KAb = (unsigned short*)(ws + 83886080);   // 8 MB
  unsigned short* KTb = (unsigned short*)(ws + 92274688);   // 8 MB
  unsigned short* VTb = (unsigned short*)(ws + 100663296);  // 16 MB (b,h,d,512)
  unsigned short* AOb = (unsigned short*)(ws + 117440512);  // 16 MB
  float* COS = (float*)(ws + 134217728);                    // 256 KB
  float* SIN = (float*)(ws + 134479872);                    // 256 KB

  cvt_f32_bf16<<<4096, 256, 0, stream>>>(x, XB, 1048576);
  cvt_f32_bf16<<<2048, 256, 0, stream>>>(h_a, HAB, 524288);
  cvt_f32_bf16<<<2048, 256, 0, stream>>>(h_t, HTB, 524288);
  const float* wsrc[8] = {W_qa, W_ka, W_va, W_qt, W_kt, W_vt, W_o, W_ffn};
  for (int i = 0; i < 8; ++i)
    cvt_w_bf16<<<512, 256, 0, stream>>>(wsrc[i], eptr, WW + (size_t)i * 1048576);
  rope_table<<<256, 256, 0, stream>>>(COS, SIN);

  gemm_bt<0, 512><<<dim3(8, 64), 256, 0, stream>>>(XB,  WW + 0ull * 1048576, b_qa, eptr, COS, SIN, QAb, 0, nullptr, nullptr);
  gemm_bt<0, 512><<<dim3(8, 64), 256, 0, stream>>>(XB,  WW + 3ull * 1048576, b_qt, eptr, COS, SIN, QTb, 0, nullptr, nullptr);
  gemm_bt<0, 256><<<dim3(8, 32), 256, 0, stream>>>(HAB, WW + 1ull * 1048576, b_ka, eptr, COS, SIN, KAb, 0, nullptr, nullptr);
  gemm_bt<0, 256><<<dim3(8, 32), 256, 0, stream>>>(HTB, WW + 4ull * 1048576, b_kt, eptr, COS, SIN, KTb, 0, nullptr, nullptr);
  gemm_bt<1, 256><<<dim3(8, 32), 256, 0, stream>>>(HAB, WW + 2ull * 1048576, b_va, eptr, nullptr, nullptr, VTb, 0,   nullptr, nullptr);
  gemm_bt<1, 256><<<dim3(8, 32), 256, 0, stream>>>(HTB, WW + 5ull * 1048576, b_vt, eptr, nullptr, nullptr, VTb, 256, nullptr, nullptr);

  attn_kernel<<<512, 256, 0, stream>>>(QAb, QTb, KAb, KTb, VTb, AOb, gating, eptr);

  gemm_bt<2, 512><<<dim3(8, 64), 256, 0, stream>>>(AOb, WW + 6ull * 1048576, b_o, eptr, nullptr, nullptr, nullptr, 0, x, X2);
  ln_kernel<<<8192, 256, 0, stream>>>(X2, gamma, beta, eptr, XN);
  gemm_bt<3, 512><<<dim3(8, 64), 256, 0, stream>>>(XN, WW + 7ull * 1048576, b_ffn, eptr, nullptr, nullptr, nullptr, 0, nullptr, (float*)d_out);
}

// Round 2
// 320.235 us; speedup vs baseline: 1.1527x; 1.1527x over previous
//
#include <hip/hip_runtime.h>
#include <stdint.h>

typedef __bf16 bf16x8 __attribute__((ext_vector_type(8)));
typedef float f32x4 __attribute__((ext_vector_type(4)));
typedef unsigned short u16x8 __attribute__((ext_vector_type(8)));

typedef const __attribute__((address_space(1))) void* gas_ptr;
typedef __attribute__((address_space(3))) void* las_ptr;

__device__ __forceinline__ void gload16(const void* g, void* l) {
  __builtin_amdgcn_global_load_lds((gas_ptr)g, (las_ptr)l, 16, 0, 0);
}

__device__ __forceinline__ unsigned short f2bf(float f) {
  uint32_t u = __float_as_uint(f);
  u += 0x7FFFu + ((u >> 16) & 1u);
  return (unsigned short)(u >> 16);
}

// ---------------- fused prep: all f32->bf16 converts + RoPE table ----------
__device__ __forceinline__ void conv8(const float* __restrict__ src,
                                      unsigned short* __restrict__ dst, int i) {
  const float4* s4 = (const float4*)src;
  float4 a = s4[2 * i], b = s4[2 * i + 1];
  u16x8 r;
  r[0] = f2bf(a.x); r[1] = f2bf(a.y); r[2] = f2bf(a.z); r[3] = f2bf(a.w);
  r[4] = f2bf(b.x); r[5] = f2bf(b.y); r[6] = f2bf(b.z); r[7] = f2bf(b.w);
  *(u16x8*)&dst[(size_t)i * 8] = r;
}

__global__ __launch_bounds__(256)
void prep_all(const float* __restrict__ x, const float* __restrict__ h_a,
              const float* __restrict__ h_t,
              const float* W0, const float* W1, const float* W2, const float* W3,
              const float* W4, const float* W5, const float* W6, const float* W7,
              const int* __restrict__ eptr,
              unsigned short* __restrict__ XB, unsigned short* __restrict__ HAB,
              unsigned short* __restrict__ HTB, unsigned short* __restrict__ WW,
              float* __restrict__ cosb, float* __restrict__ sinb) {
  const int blk = blockIdx.x, tid = threadIdx.x;
  if (blk < 4096) {
    conv8(x, XB, blk * 256 + tid);
  } else if (blk < 6144) {
    conv8(h_a, HAB, (blk - 4096) * 256 + tid);
  } else if (blk < 8192) {
    conv8(h_t, HTB, (blk - 6144) * 256 + tid);
  } else if (blk < 12288) {
    const int w = (blk - 8192) >> 9;
    const int i = ((blk - 8192) & 511) * 256 + tid;
    const float* wp;
    switch (w) {
      case 0: wp = W0; break; case 1: wp = W1; break;
      case 2: wp = W2; break; case 3: wp = W3; break;
      case 4: wp = W4; break; case 5: wp = W5; break;
      case 6: wp = W6; break; default: wp = W7; break;
    }
    conv8(wp + (size_t)(*eptr) * 1048576, WW + (size_t)w * 1048576, i);
  } else {
    const int i = (blk - 12288) * 256 + tid;  // 0..65535
    const int t = i >> 7, d = i & 127;
    const int f = d & 63;
    float invf = expf(-0.14391156831212787f * (float)f);  // 10000^(-f/64)
    float ang = (float)t * invf;
    float s, c;
    sincosf(ang, &s, &c);
    cosb[i] = c;
    sinb[i] = s;
  }
}

// ---------------- GEMM: C[M,1024] = A[M,1024] * W[1024,1024]^T (+epilogue) ----
// m97 structure: 128x128 tile, BK=32, 4 waves (2x2), global_load_lds w=16.
// EPI 0: +bias, RoPE, store bf16 (b,h,t,d).   LSEQ in {512,256}
// EPI 1: +bias, store bf16 transposed vT (b,h,d, voff+n)
// EPI 2: +bias +resid, store f32
// EPI 3: +bias, relu, store f32
template <int EPI, int LSEQ>
__global__ __launch_bounds__(256)
void gemm_bt(const unsigned short* __restrict__ A, const unsigned short* __restrict__ Wb,
             const float* __restrict__ bias_base, const int* __restrict__ eptr,
             const float* __restrict__ ctab, const float* __restrict__ stab,
             unsigned short* __restrict__ out_bf, int voff,
             const float* __restrict__ resid, float* __restrict__ out_f32) {
  __shared__ unsigned short As[128 * 32];
  __shared__ unsigned short Bs[128 * 32];
  const int tid = threadIdx.x, lane = tid & 63, wv = tid >> 6;
  const int wr = wv >> 1, wc = wv & 1;
  const int bn = blockIdx.x, bm = blockIdx.y;
  const int e = *eptr;
  const float* bias = bias_base + e * 1024;
  const int srow = tid >> 2, scol = (tid & 3) << 3;
  const unsigned short* Ag = A + (size_t)(bm * 128 + srow) * 1024 + scol;
  const unsigned short* Bg = Wb + (size_t)(bn * 128 + srow) * 1024 + scol;
  unsigned short* Asd = As + tid * 8;
  unsigned short* Bsd = Bs + tid * 8;

  f32x4 acc[4][4];
#pragma unroll
  for (int m = 0; m < 4; ++m)
#pragma unroll
    for (int n = 0; n < 4; ++n) acc[m][n] = f32x4{0.f, 0.f, 0.f, 0.f};

  const int fr = lane & 15, ko = (lane >> 4) << 3;
  for (int kt = 0; kt < 1024; kt += 32) {
    gload16(Ag + kt, Asd);
    gload16(Ag + kt + 65536, Asd + 2048);
    gload16(Bg + kt, Bsd);
    gload16(Bg + kt + 65536, Bsd + 2048);
    __syncthreads();
    bf16x8 af[4], bw[4];
#pragma unroll
    for (int m = 0; m < 4; ++m)
      af[m] = *(const bf16x8*)&As[(wr * 64 + m * 16 + fr) * 32 + ko];
#pragma unroll
    for (int n = 0; n < 4; ++n)
      bw[n] = *(const bf16x8*)&Bs[(wc * 64 + n * 16 + fr) * 32 + ko];
#pragma unroll
    for (int m = 0; m < 4; ++m)
#pragma unroll
      for (int n = 0; n < 4; ++n)
        acc[m][n] = __builtin_amdgcn_mfma_f32_16x16x32_bf16(af[m], bw[n], acc[m][n], 0, 0, 0);
    __syncthreads();
  }

  const int g = lane >> 4;
#pragma unroll
  for (int m = 0; m < 4; ++m) {
#pragma unroll
    for (int n = 0; n < 4; ++n) {
      const int gcol = bn * 128 + wc * 64 + n * 16 + fr;
      const float bv = bias[gcol];
#pragma unroll
      for (int j = 0; j < 4; ++j) {
        const int grow = bm * 128 + wr * 64 + m * 16 + g * 4 + j;
        float v = acc[m][n][j] + bv;
        if constexpr (EPI == 0) {
          constexpr int SH = (LSEQ == 512) ? 9 : 8;
          const int t = grow & (LSEQ - 1);
          const int bb = grow >> SH;
          const int hh = gcol >> 7, dd = gcol & 127;
          float pv = __shfl_xor(v, 1);  // partner column (d^1), incl. its bias
          float cs = ctab[t * 128 + dd], sn = stab[t * 128 + dd];
          float rh = (dd & 1) ? pv : -pv;  // rotate_half interleaved
          float o = v * cs + rh * sn;
          out_bf[(((size_t)(bb * 8 + hh) * LSEQ + t) << 7) + dd] = f2bf(o);
        } else if constexpr (EPI == 1) {
          const int nn = grow & 255, bb = grow >> 8;
          const int hh = gcol >> 7, dd = gcol & 127;
          out_bf[(((size_t)(bb * 8 + hh) << 7) + (size_t)dd) * 512 + voff + nn] = f2bf(v);
        } else if constexpr (EPI == 2) {
          const size_t idx = ((size_t)grow << 10) + gcol;
          out_f32[idx] = v + resid[idx];
        } else {
          const size_t idx = ((size_t)grow << 10) + gcol;
          out_f32[idx] = fmaxf(v, 0.f);
        }
      }
    }
  }
}

// ---------------- fused dual-stream flash attention (async double-buffered) --
// grid: 512 blocks = (b:16, h:8, q-chunk:4 of 128 rows); 256 thr = 4 waves
// KV tiles of 64: tiles 0-3 -> (QA,KA,V[0:256]), tiles 4-7 -> (QT,KT,V[256:512])
// Q lives in registers (loaded direct from global). K/V double-buffered in LDS
// via global_load_lds with pre-swizzled SOURCE (linear LDS dest), counted
// vmcnt + raw s_barrier so prefetch loads stay in flight across barriers.
__global__ __launch_bounds__(256, 2)
void attn_kernel(const unsigned short* __restrict__ QA, const unsigned short* __restrict__ QT,
                 const unsigned short* __restrict__ KA, const unsigned short* __restrict__ KT,
                 const unsigned short* __restrict__ VT,  // (b,h,d=128,n=512)
                 unsigned short* __restrict__ AO,        // (b,t,1024)
                 const float* __restrict__ gating, const int* __restrict__ eptr) {
  __shared__ unsigned short Ks[2][8192];  // 2 x 16 KB, rows of 256B, chunk-swizzled
  __shared__ unsigned short Vs[2][8192];  // 2 x 16 KB, [d][n] rows of 128B
  __shared__ unsigned short Ps[8192];     // 16 KB
  const int tid = threadIdx.x, lane = tid & 63, wv = tid >> 6;
  const int fr = lane & 15, g = lane >> 4;
  const int bid = blockIdx.x;
  const int b = bid >> 5, h = (bid >> 2) & 7, q0 = (bid & 3) << 7;
  const float ratio = 1.f / (1.f + __expf(-gating[*eptr]));
  const float SC = 0.08838834764831845f;  // 1/sqrt(128)
  const size_t bh = (size_t)(b * 8 + h);

  // Q fragments straight to registers (row = q0 + wv*32 + mb*16 + fr)
  bf16x8 qf[2][4], qTr[2][4];
  {
    const char* qa = (const char*)QA + ((bh * 512 + q0 + wv * 32 + fr) << 8) + g * 16;
    const char* qt = (const char*)QT + ((bh * 512 + q0 + wv * 32 + fr) << 8) + g * 16;
#pragma unroll
    for (int mb = 0; mb < 2; ++mb)
#pragma unroll
      for (int kb = 0; kb < 4; ++kb) {
        qf[mb][kb]  = *(const bf16x8*)(qa + mb * 4096 + kb * 64);
        qTr[mb][kb] = *(const bf16x8*)(qt + mb * 4096 + kb * 64);
      }
  }

  // async stage of one KV tile (8 x gload16 per thread = 32 KB per block)
  // LDS dest linear; global source chunk index XOR'd with row so that the
  // swizzled reader (byte ^ ((row&7)<<4)) sees logical data.
  auto stage = [&](int t, int buf) {
    const char* kgb = (const char*)((t < 4) ? KA : KT) + ((bh * 256 + ((size_t)(t & 3) << 6)) << 8);
    const char* vgb = (const char*)VT + (bh << 17) + (t << 7);
    char* ksd = (char*)Ks[buf] + tid * 16;
    char* vsd = (char*)Vs[buf] + tid * 16;
#pragma unroll
    for (int j = 0; j < 4; ++j) {
      const int rk = j * 16 + (tid >> 4);
      const int ck = ((tid & 15) << 4) ^ ((rk & 7) << 4);
      gload16(kgb + rk * 256 + ck, ksd + j * 4096);
      const int dv = j * 32 + (tid >> 3);
      const int cv = ((tid & 7) << 4) ^ ((dv & 7) << 4);
      gload16(vgb + dv * 1024 + cv, vsd + j * 4096);
    }
  };

  float m_run[2][4], l_run[2][4];
  f32x4 oacc[2][8];
#pragma unroll
  for (int mb = 0; mb < 2; ++mb) {
#pragma unroll
    for (int j = 0; j < 4; ++j) { m_run[mb][j] = -1e30f; l_run[mb][j] = 0.f; }
#pragma unroll
    for (int db = 0; db < 8; ++db) oacc[mb][db] = f32x4{0.f, 0.f, 0.f, 0.f};
  }

  stage(0, 0);

  for (int it = 0; it < 8; ++it) {
    const int cur = it & 1;
    if (it < 7) stage(it + 1, cur ^ 1);
    __builtin_amdgcn_sched_barrier(0);
    if (it < 7) asm volatile("s_waitcnt vmcnt(8)");  // cur tile staged; next stays in flight
    else        asm volatile("s_waitcnt vmcnt(0)");
    __builtin_amdgcn_sched_barrier(0);
    __builtin_amdgcn_s_barrier();
    __builtin_amdgcn_sched_barrier(0);

    if (it == 4) {
#pragma unroll
      for (int mb = 0; mb < 2; ++mb)
#pragma unroll
        for (int kb = 0; kb < 4; ++kb) qf[mb][kb] = qTr[mb][kb];
    }
    const float sc = (it < 4) ? SC : SC * ratio;
    const char* kc = (const char*)Ks[cur];
    const char* vc = (const char*)Vs[cur];

    // S = Q K^T  (wave's 32 rows x 64 cols)
    f32x4 s[2][4];
#pragma unroll
    for (int mb = 0; mb < 2; ++mb)
#pragma unroll
      for (int nb = 0; nb < 4; ++nb) s[mb][nb] = f32x4{0.f, 0.f, 0.f, 0.f};
#pragma unroll
    for (int nb = 0; nb < 4; ++nb) {
#pragma unroll
      for (int kb = 0; kb < 4; ++kb) {
        const int r = nb * 16 + fr;
        const int byt = (r * 256 + kb * 64 + g * 16) ^ ((r & 7) << 4);
        bf16x8 kf = *(const bf16x8*)(kc + byt);
        s[0][nb] = __builtin_amdgcn_mfma_f32_16x16x32_bf16(qf[0][kb], kf, s[0][nb], 0, 0, 0);
        s[1][nb] = __builtin_amdgcn_mfma_f32_16x16x32_bf16(qf[1][kb], kf, s[1][nb], 0, 0, 0);
      }
    }
    // scale + online softmax (reduce over 16-lane group = kv cols)
    float mt[2][4];
#pragma unroll
    for (int mb = 0; mb < 2; ++mb)
#pragma unroll
      for (int j = 0; j < 4; ++j) {
        float mx = -1e30f;
#pragma unroll
        for (int nb = 0; nb < 4; ++nb) {
          s[mb][nb][j] *= sc;
          mx = fmaxf(mx, s[mb][nb][j]);
        }
        mt[mb][j] = mx;
      }
#pragma unroll
    for (int mb = 0; mb < 2; ++mb)
#pragma unroll
      for (int j = 0; j < 4; ++j) {
#pragma unroll
        for (int d = 1; d < 16; d <<= 1) mt[mb][j] = fmaxf(mt[mb][j], __shfl_xor(mt[mb][j], d));
        float mn = fmaxf(m_run[mb][j], mt[mb][j]);
        float alpha = __expf(m_run[mb][j] - mn);
        m_run[mb][j] = mn;
        l_run[mb][j] *= alpha;
#pragma unroll
        for (int db = 0; db < 8; ++db) oacc[mb][db][j] *= alpha;
      }
    // P = exp(S - m); write bf16 to swizzled LDS (packed col pairs)
#pragma unroll
    for (int mb = 0; mb < 2; ++mb)
#pragma unroll
      for (int nb = 0; nb < 4; ++nb) {
        float p[4], po[4];
#pragma unroll
        for (int j = 0; j < 4; ++j) {
          p[j] = __expf(s[mb][nb][j] - m_run[mb][j]);
          l_run[mb][j] += p[j];
        }
#pragma unroll
        for (int j = 0; j < 4; ++j) po[j] = __shfl_xor(p[j], 1);
        if ((lane & 1) == 0) {
#pragma unroll
          for (int j = 0; j < 4; ++j) {
            uint32_t pk = (uint32_t)f2bf(p[j]) | ((uint32_t)f2bf(po[j]) << 16);
            const int r = wv * 32 + mb * 16 + g * 4 + j;
            const int byt = (r * 128 + (nb * 16 + fr) * 2) ^ ((r & 7) << 4);
            *(uint32_t*)((char*)Ps + byt) = pk;
          }
        }
      }
    // O += P * V  (Ps wave-local write->read; compiler orders via lgkmcnt)
#pragma unroll
    for (int kb2 = 0; kb2 < 2; ++kb2) {
      bf16x8 pf[2];
#pragma unroll
      for (int mb = 0; mb < 2; ++mb) {
        const int r = wv * 32 + mb * 16 + fr;
        const int byt = (r * 128 + kb2 * 64 + g * 16) ^ ((r & 7) << 4);
        pf[mb] = *(const bf16x8*)((const char*)Ps + byt);
      }
#pragma unroll
      for (int db = 0; db < 8; ++db) {
        const int rv = db * 16 + fr;
        const int byt = (rv * 128 + kb2 * 64 + g * 16) ^ ((rv & 7) << 4);
        bf16x8 vf = *(const bf16x8*)(vc + byt);
        oacc[0][db] = __builtin_amdgcn_mfma_f32_16x16x32_bf16(pf[0], vf, oacc[0][db], 0, 0, 0);
        oacc[1][db] = __builtin_amdgcn_mfma_f32_16x16x32_bf16(pf[1], vf, oacc[1][db], 0, 0, 0);
      }
    }
    __builtin_amdgcn_sched_barrier(0);
    __builtin_amdgcn_s_barrier();  // protect buf cur before next iter re-stages it
  }

  // finalize: reduce l over 16-lane group, normalize, store
#pragma unroll
  for (int mb = 0; mb < 2; ++mb)
#pragma unroll
    for (int j = 0; j < 4; ++j) {
      float lt = l_run[mb][j];
#pragma unroll
      for (int d = 1; d < 16; d <<= 1) lt += __shfl_xor(lt, d);
      float inv = 1.f / lt;
#pragma unroll
      for (int db = 0; db < 8; ++db) {
        float o = oacc[mb][db][j] * inv;
        int row = q0 + wv * 32 + mb * 16 + g * 4 + j;
        int col = h * 128 + db * 16 + fr;
        AO[(((size_t)b * 512 + row) << 10) + col] = f2bf(o);
      }
    }
}

// ---------------- LayerNorm (rows of 1024) ----------------
__global__ __launch_bounds__(256)
void ln_kernel(const float* __restrict__ X2, const float* __restrict__ gbase,
               const float* __restrict__ bbase, const int* __restrict__ eptr,
               unsigned short* __restrict__ XN) {
  const int row = blockIdx.x, tid = threadIdx.x;
  const float* x = X2 + ((size_t)row << 10);
  float4 v = ((const float4*)x)[tid];
  float s = v.x + v.y + v.z + v.w;
  float ss = v.x * v.x + v.y * v.y + v.z * v.z + v.w * v.w;
#pragma unroll
  for (int d = 1; d < 64; d <<= 1) {
    s += __shfl_xor(s, d);
    ss += __shfl_xor(ss, d);
  }
  __shared__ float red[8];
  const int wv = tid >> 6, lane = tid & 63;
  if (lane == 0) { red[wv] = s; red[4 + wv] = ss; }
  __syncthreads();
  s = red[0] + red[1] + red[2] + red[3];
  ss = red[4] + red[5] + red[6] + red[7];
  const float mu = s * 0.0009765625f;
  const float var = ss * 0.0009765625f - mu * mu;
  const float inv = rsqrtf(var + 1e-5f);
  const int e = *eptr;
  const float* gg = gbase + e * 1024 + tid * 4;
  const float* bb = bbase + e * 1024 + tid * 4;
  ushort4 o;
  o.x = f2bf((v.x - mu) * inv * gg[0] + bb[0]);
  o.y = f2bf((v.y - mu) * inv * gg[1] + bb[1]);
  o.z = f2bf((v.z - mu) * inv * gg[2] + bb[2]);
  o.w = f2bf((v.w - mu) * inv * gg[3] + bb[3]);
  *(ushort4*)&XN[((size_t)row << 10) + tid * 4] = o;
}

// ---------------- host launcher ----------------
extern "C" void kernel_launch(void* const* d_in, const int* in_sizes, int n_in,
                              void* d_out, int out_size, void* d_ws, size_t ws_size,
                              hipStream_t stream) {
  (void)in_sizes; (void)n_in; (void)out_size; (void)ws_size;
  const float* x      = (const float*)d_in[0];
  const float* h_a    = (const float*)d_in[1];
  const float* h_t    = (const float*)d_in[2];
  const float* W_qa   = (const float*)d_in[3];
  const float* b_qa   = (const float*)d_in[4];
  const float* W_ka   = (const float*)d_in[5];
  const float* b_ka   = (const float*)d_in[6];
  const float* W_va   = (const float*)d_in[7];
  const float* b_va   = (const float*)d_in[8];
  const float* W_qt   = (const float*)d_in[9];
  const float* b_qt   = (const float*)d_in[10];
  const float* W_kt   = (const float*)d_in[11];
  const float* b_kt   = (const float*)d_in[12];
  const float* W_vt   = (const float*)d_in[13];
  const float* b_vt   = (const float*)d_in[14];
  const float* W_o    = (const float*)d_in[15];
  const float* b_o    = (const float*)d_in[16];
  const float* W_ffn  = (const float*)d_in[17];
  const float* b_ffn  = (const float*)d_in[18];
  const float* gamma  = (const float*)d_in[19];
  const float* beta   = (const float*)d_in[20];
  const float* gating = (const float*)d_in[21];
  const int*   eptr   = (const int*)d_in[22];

  char* ws = (char*)d_ws;
  unsigned short* XB  = (unsigned short*)(ws + 0);          // 16 MB (x bf16)
  unsigned short* HAB = (unsigned short*)(ws + 16777216);   // 8 MB
  unsigned short* HTB = (unsigned short*)(ws + 25165824);   // 8 MB
  float*          X2  = (float*)(ws + 0);                   // 32 MB, overlays XB/HAB/HTB (dead by then)
  unsigned short* WW  = (unsigned short*)(ws + 33554432);   // 8 x 2 MB bf16 weights
  unsigned short* QAb = (unsigned short*)(ws + 50331648);   // 16 MB
  unsigned short* XN  = QAb;                                // overlays QA (dead after attn)
  unsigned short* QTb = (unsigned short*)(ws + 67108864);   // 16 MB
  unsigned short* KAb = (unsigned short*)(ws + 83886080);   // 8 MB
  unsigned short* KTb = (unsigned short*)(ws + 92274688);   // 8 MB
  unsigned short* VTb = (unsigned short*)(ws + 100663296);  // 16 MB (b,h,d,512)
  unsigned short* AOb = (unsigned short*)(ws + 117440512);  // 16 MB
  float* COS = (float*)(ws + 134217728);                    // 256 KB
  float* SIN = (float*)(ws + 134479872);                    // 256 KB

  prep_all<<<12544, 256, 0, stream>>>(x, h_a, h_t,
      W_qa, W_ka, W_va, W_qt, W_kt, W_vt, W_o, W_ffn, eptr,
      XB, HAB, HTB, WW, COS, SIN);

  gemm_bt<0, 512><<<dim3(8, 64), 256, 0, stream>>>(XB,  WW + 0ull * 1048576, b_qa, eptr, COS, SIN, QAb, 0, nullptr, nullptr);
  gemm_bt<0, 512><<<dim3(8, 64), 256, 0, stream>>>(XB,  WW + 3ull * 1048576, b_qt, eptr, COS, SIN, QTb, 0, nullptr, nullptr);
  gemm_bt<0, 256><<<dim3(8, 32), 256, 0, stream>>>(HAB, WW + 1ull * 1048576, b_ka, eptr, COS, SIN, KAb, 0, nullptr, nullptr);
  gemm_bt<0, 256><<<dim3(8, 32), 256, 0, stream>>>(HTB, WW + 4ull * 1048576, b_kt, eptr, COS, SIN, KTb, 0, nullptr, nullptr);
  gemm_bt<1, 256><<<dim3(8, 32), 256, 0, stream>>>(HAB, WW + 2ull * 1048576, b_va, eptr, nullptr, nullptr, VTb, 0,   nullptr, nullptr);
  gemm_bt<1, 256><<<dim3(8, 32), 256, 0, stream>>>(HTB, WW + 5ull * 1048576, b_vt, eptr, nullptr, nullptr, VTb, 256, nullptr, nullptr);

  attn_kernel<<<512, 256, 0, stream>>>(QAb, QTb, KAb, KTb, VTb, AOb, gating, eptr);

  gemm_bt<2, 512><<<dim3(8, 64), 256, 0, stream>>>(AOb, WW + 6ull * 1048576, b_o, eptr, nullptr, nullptr, nullptr, 0, x, X2);
  ln_kernel<<<8192, 256, 0, stream>>>(X2, gamma, beta, eptr, XN);
  gemm_bt<3, 512><<<dim3(8, 64), 256, 0, stream>>>(XN, WW + 7ull * 1048576, b_ffn, eptr, nullptr, nullptr, nullptr, 0, nullptr, (float*)d_out);
}